// Round 1
// baseline (986.188 us; speedup 1.0000x reference)
//
#include <hip/hip_runtime.h>

// EQL forward for MI355X. Structure:
//   kernel 1 (mask):  constw[s,o,j] = constw_base[o,j] * ((hard - soft) + soft)   -> d_ws
//   kernel 2 (main):  one block per (s,o,chunk); one thread per batch row.
//                     hidden[94] fully unrolled in VGPRs; weights read via
//                     wave-uniform (scalar) loads from d_ws. regu partial -> f64 atomic.
//   kernel 3 (fin):   out[983040] = regu_sum / (S*B*O)

#define S_NUM 16
#define O_NUM 15
#define B_NUM 4096
#define NET_IN 64
#define WSHAPE 3120
#define BSHAPE 41
#define TEMP_F 0.03f
#define EPS_F 1e-20f
#define OUT_ELEMS (S_NUM * B_NUM * O_NUM)   // 983040

// ---------------------------------------------------------------- mask kernel
__global__ __launch_bounds__(256) void eql_mask_kernel(
    const float* __restrict__ scores, const float* __restrict__ constw_base,
    const float* __restrict__ u0, const float* __restrict__ u1,
    float* __restrict__ wsw)
{
  int idx = blockIdx.x * 256 + threadIdx.x;
  if (idx >= S_NUM * O_NUM * WSHAPE) return;
  int oj = idx % (O_NUM * WSHAPE);

  float a0 = u0[idx], a1 = u1[idx];
  float noise = -logf(logf(a0 + EPS_F) / logf(a1 + EPS_F) + EPS_F);
  float sc = scores[oj];
  float cs = 1.0f / (1.0f + expf(-sc));
  float arg = (logf(cs + EPS_F) - logf(1.0f - cs + EPS_F) + noise) * TEMP_F;
  float soft = 1.0f / (1.0f + expf(-arg));
  float hard = (soft > 0.5f) ? 1.0f : 0.0f;
  // forward value of hard - stop_gradient(soft) + soft, replicated exactly
  wsw[idx] = constw_base[oj] * ((hard - soft) + soft);
}

// ---------------------------------------------------------------- ops
__device__ __forceinline__ float clip100(float x) {
  return fminf(fmaxf(x, -100.f), 100.f);
}
__device__ __forceinline__ float op_mul(float a, float b, float& r) {
  r += fmaxf(-100.f - a, 0.f) + fmaxf(a - 100.f, 0.f)
     + fmaxf(-100.f - b, 0.f) + fmaxf(b - 100.f, 0.f);
  return clip100(a) * clip100(b);
}
__device__ __forceinline__ float op_div(float a, float b, float& r) {
  r += fmaxf(0.01f - b, 0.f);
  return (b < 0.01f) ? 0.f : a / b;
}
__device__ __forceinline__ float op_log(float a, float& r) {
  r += fmaxf(0.001f - a, 0.f);
  return logf(fmaxf(a, 0.001f));
}
__device__ __forceinline__ float op_exp(float a, float& r) {
  r += fmaxf(-10.f - a, 0.f) + fmaxf(a - 4.f, 0.f);
  return expf(fminf(fmaxf(a, -10.f), 4.f));
}

// matmul macro: pre[e] = bb[BLO+e] + sum_d h[d] * w[WLO + d*INALL + e]
// fully unrolled -> compile-time indices -> h stays in VGPRs, w loads uniform.
#define DO_MM(INS, INALL, WLO, BLO, P)                                   \
  float P[INALL];                                                        \
  _Pragma("unroll") for (int e = 0; e < (INALL); e++) P[e] = bb[(BLO) + e]; \
  _Pragma("unroll") for (int d = 0; d < (INS); d++) {                    \
    float hd = h[d];                                                     \
    _Pragma("unroll") for (int e = 0; e < (INALL); e++)                  \
      P[e] = fmaf(w[(WLO) + d * (INALL) + e], hd, P[e]);                 \
  }

// ---------------------------------------------------------------- main kernel
__global__ __launch_bounds__(256) void eql_main_kernel(
    const float* __restrict__ obs, const float* __restrict__ constb,
    const float* __restrict__ wsw, float* __restrict__ out,
    double* __restrict__ regu_acc)
{
  int blk = blockIdx.x;
  int chunk = blk & 15;          // 16 chunks of 256 batch rows
  int so = blk >> 4;             // 0..239
  int o = so % O_NUM;
  int s = so / O_NUM;

  const float* __restrict__ w  = wsw + (size_t)so * WSHAPE;  // wave-uniform
  const float* __restrict__ bb = constb + o * BSHAPE;        // wave-uniform

  int b = chunk * 256 + threadIdx.x;

  float h[94];
  const float4* o4 = reinterpret_cast<const float4*>(obs + (size_t)b * NET_IN);
#pragma unroll
  for (int i = 0; i < 16; i++) {
    float4 v = o4[i];
    h[4 * i] = v.x; h[4 * i + 1] = v.y; h[4 * i + 2] = v.z; h[4 * i + 3] = v.w;
  }

  float regu = 0.f;

  { // layer 0: mul,mul,mul          ins=64 inall=6 wlo=0    blo=0
    DO_MM(64, 6, 0, 0, p)
    h[64] = op_mul(p[0], p[1], regu);
    h[65] = op_mul(p[2], p[3], regu);
    h[66] = op_mul(p[4], p[5], regu);
  }
  { // layer 1: div,div,div          ins=67 inall=6 wlo=384  blo=6
    DO_MM(67, 6, 384, 6, p)
    h[67] = op_div(p[0], p[1], regu);
    h[68] = op_div(p[2], p[3], regu);
    h[69] = op_div(p[4], p[5], regu);
  }
  { // layer 2: log,log,exp,exp,sin,sin,cos,cos  ins=70 inall=8 wlo=786 blo=12
    DO_MM(70, 8, 786, 12, p)
    h[70] = op_log(p[0], regu);
    h[71] = op_log(p[1], regu);
    h[72] = op_exp(p[2], regu);
    h[73] = op_exp(p[3], regu);
    h[74] = sinf(p[4]);
    h[75] = sinf(p[5]);
    h[76] = cosf(p[6]);
    h[77] = cosf(p[7]);
  }
  { // layer 3: same                 ins=78 inall=8 wlo=1346 blo=20
    DO_MM(78, 8, 1346, 20, p)
    h[78] = op_log(p[0], regu);
    h[79] = op_log(p[1], regu);
    h[80] = op_exp(p[2], regu);
    h[81] = op_exp(p[3], regu);
    h[82] = sinf(p[4]);
    h[83] = sinf(p[5]);
    h[84] = cosf(p[6]);
    h[85] = cosf(p[7]);
  }
  { // layer 4: mul,div,log,exp      ins=86 inall=6 wlo=1970 blo=28
    DO_MM(86, 6, 1970, 28, p)
    h[86] = op_mul(p[0], p[1], regu);
    h[87] = op_div(p[2], p[3], regu);
    h[88] = op_log(p[4], regu);
    h[89] = op_exp(p[5], regu);
  }
  { // layer 5: mul,div,log,exp      ins=90 inall=6 wlo=2486 blo=34
    DO_MM(90, 6, 2486, 34, p)
    h[90] = op_mul(p[0], p[1], regu);
    h[91] = op_div(p[2], p[3], regu);
    h[92] = op_log(p[4], regu);
    h[93] = op_exp(p[5], regu);
  }

  // final: ins=94, 1 output, wlo=3026, blo=40
  float res = bb[40];
#pragma unroll
  for (int d = 0; d < 94; d++) res = fmaf(w[3026 + d], h[d], res);

  out[((size_t)s * B_NUM + b) * O_NUM + o] = res;

  // ---- regu block reduction -> one f64 atomic per block
#pragma unroll
  for (int off = 32; off > 0; off >>= 1) regu += __shfl_down(regu, off);
  __shared__ float wsum[4];
  if ((threadIdx.x & 63) == 0) wsum[threadIdx.x >> 6] = regu;
  __syncthreads();
  if (threadIdx.x == 0) {
    float t = wsum[0] + wsum[1] + wsum[2] + wsum[3];
    atomicAdd(regu_acc, (double)t);
  }
}

// ---------------------------------------------------------------- finalize
__global__ void eql_finalize_kernel(const double* __restrict__ regu_acc,
                                    float* __restrict__ out)
{
  out[OUT_ELEMS] = (float)(*regu_acc / (double)OUT_ELEMS);
}

// ---------------------------------------------------------------- launch
extern "C" void kernel_launch(void* const* d_in, const int* in_sizes, int n_in,
                              void* d_out, int out_size, void* d_ws, size_t ws_size,
                              hipStream_t stream) {
  const float* obs    = (const float*)d_in[0];
  const float* scores = (const float*)d_in[1];
  const float* cwb    = (const float*)d_in[2];
  const float* constb = (const float*)d_in[3];
  const float* u0     = (const float*)d_in[4];
  const float* u1     = (const float*)d_in[5];
  float* out = (float*)d_out;

  double* regu = (double*)d_ws;                       // 8 B accumulator
  float*  wsw  = (float*)((char*)d_ws + 256);         // 16*15*3120 floats ~ 3 MB

  hipMemsetAsync(regu, 0, sizeof(double), stream);

  int n_mask = S_NUM * O_NUM * WSHAPE;                // 748800
  eql_mask_kernel<<<(n_mask + 255) / 256, 256, 0, stream>>>(scores, cwb, u0, u1, wsw);

  eql_main_kernel<<<S_NUM * O_NUM * (B_NUM / 256), 256, 0, stream>>>(
      obs, constb, wsw, out, regu);

  eql_finalize_kernel<<<1, 1, 0, stream>>>(regu, out);
}